// Round 4
// baseline (502.448 us; speedup 1.0000x reference)
//
#include <hip/hip_runtime.h>
#include <stdint.h>

#define DEVI static __device__ __forceinline__

typedef __attribute__((ext_vector_type(8))) short short8;
typedef __attribute__((ext_vector_type(4))) float floatx4;
typedef __attribute__((ext_vector_type(4))) unsigned short ushortx4;

// ---------- bf16 helpers ----------
DEVI unsigned short f2bf(float f) {
  union { float f; uint32_t u; } v; v.f = f;
  uint32_t r = v.u + 0x7FFFu + ((v.u >> 16) & 1u);
  return (unsigned short)(r >> 16);
}
DEVI float bf2f(unsigned short s) {
  union { uint32_t u; float f; } v; v.u = ((uint32_t)s) << 16;
  return v.f;
}

// ---------- async global->LDS 16B ----------
DEVI void lds_cp16(void* lds, const void* g) {
  __builtin_amdgcn_global_load_lds(
      (const __attribute__((address_space(1))) uint32_t*)g,
      reinterpret_cast<__attribute__((address_space(3))) uint32_t*>(
          (uint32_t)reinterpret_cast<uintptr_t>(lds)),
      16, 0, 0);
}

// =====================================================================
// f32 -> bf16 elementwise
// =====================================================================
__global__ __launch_bounds__(256) void cvt_bf16(const float* __restrict__ X,
                                                unsigned short* __restrict__ Y) {
  const size_t i = (size_t)blockIdx.x * 256 + threadIdx.x;
  const floatx4 v = ((const floatx4*)X)[i];
  ushortx4 o;
  o.x = f2bf(v.x); o.y = f2bf(v.y); o.z = f2bf(v.z); o.w = f2bf(v.w);
  ((ushortx4*)Y)[i] = o;
}

// =====================================================================
// All 4 weight transposes in one launch. z: 0=Wq,1=Wk,2=Wv,3=Wo.
// =====================================================================
__global__ __launch_bounds__(256) void wtrans4(const float* __restrict__ Wq,
                                               const float* __restrict__ Wk,
                                               const float* __restrict__ Wv,
                                               const float* __restrict__ Wo,
                                               unsigned short* __restrict__ Wt) {
  __shared__ float t[32][33];
  const int tx = threadIdx.x, ty = threadIdx.y;
  const int z = blockIdx.z;
  const float* W = (z == 0) ? Wq : (z == 1) ? Wk : (z == 2) ? Wv : Wo;
  unsigned short* D = Wt + (size_t)z * 1024 * 1024;
  const int c0 = blockIdx.x * 32, r0 = blockIdx.y * 32;
#pragma unroll
  for (int i = 0; i < 4; i++)
    t[ty + i * 8][tx] = W[(size_t)(r0 + ty + i * 8) * 1024 + c0 + tx];
  __syncthreads();
#pragma unroll
  for (int i = 0; i < 4; i++)
    D[(size_t)(c0 + ty + i * 8) * 1024 + r0 + tx] = f2bf(t[tx][ty + i * 8]);
}

// =====================================================================
// GEMM 256x128 tile (Q / Wo projections): C[M][1024] = A @ Bt^T + bias
// 256 threads, 4 waves of 128x64 (acc[8][4]), BK=32, single-barrier dbuf.
// EPI: 0 = bf16 rowmajor, 1 = f32 rowmajor
// =====================================================================
template <int EPI>
__global__ __launch_bounds__(256, 3) void gemm_bt(
    const unsigned short* __restrict__ A, const unsigned short* __restrict__ Bt,
    const float* __restrict__ bias, void* __restrict__ Cout) {
  __shared__ unsigned short As[2][4][256][8];  // 32 KB
  __shared__ unsigned short Bs[2][4][128][8];  // 16 KB

  const int tid = threadIdx.x;
  const int lane = tid & 63, w = tid >> 6;
  const int wr = w >> 1, wc = w & 1;
  const int qd = lane >> 4, l16 = lane & 15;
  const int m0 = blockIdx.y * 256, n0 = blockIdx.x * 128;

  floatx4 acc[8][4];
#pragma unroll
  for (int i = 0; i < 8; i++)
#pragma unroll
    for (int j = 0; j < 4; j++) { floatx4 z = {0.f, 0.f, 0.f, 0.f}; acc[i][j] = z; }

  const unsigned short* aptr = A + (size_t)(m0 + tid) * 1024;
  const int brow = tid & 127, bc0 = tid >> 7;
  const unsigned short* bptr = Bt + (size_t)(n0 + brow) * 1024 + bc0 * 8;

#pragma unroll
  for (int c = 0; c < 4; c++) lds_cp16(&As[0][c][tid][0], aptr + c * 8);
  lds_cp16(&Bs[0][bc0][brow][0], bptr);
  lds_cp16(&Bs[0][bc0 + 2][brow][0], bptr + 16);

  for (int it = 0; it < 32; it++) {
    __syncthreads();
    if (it < 31) {
      const int nb = (it + 1) & 1, k0 = (it + 1) * 32;
#pragma unroll
      for (int c = 0; c < 4; c++) lds_cp16(&As[nb][c][tid][0], aptr + k0 + c * 8);
      lds_cp16(&Bs[nb][bc0][brow][0], bptr + k0);
      lds_cp16(&Bs[nb][bc0 + 2][brow][0], bptr + k0 + 16);
    }
    const int cur = it & 1;
    short8 af[8], bf[4];
#pragma unroll
    for (int mi = 0; mi < 8; mi++)
      af[mi] = *(const short8*)&As[cur][qd][wr * 128 + mi * 16 + l16][0];
#pragma unroll
    for (int ni = 0; ni < 4; ni++)
      bf[ni] = *(const short8*)&Bs[cur][qd][wc * 64 + ni * 16 + l16][0];
#pragma unroll
    for (int mi = 0; mi < 8; mi++)
#pragma unroll
      for (int ni = 0; ni < 4; ni++)
        acc[mi][ni] =
            __builtin_amdgcn_mfma_f32_16x16x32_bf16(af[mi], bf[ni], acc[mi][ni], 0, 0, 0);
  }

#pragma unroll
  for (int mi = 0; mi < 8; mi++) {
#pragma unroll
    for (int ni = 0; ni < 4; ni++) {
      const int row = m0 + wr * 128 + mi * 16 + qd * 4;
      const int col = n0 + wc * 64 + ni * 16 + l16;
      const float bv = bias[col];
      if constexpr (EPI == 0) {
        unsigned short* C = (unsigned short*)Cout;
#pragma unroll
        for (int r = 0; r < 4; r++)
          C[(size_t)(row + r) * 1024 + col] = f2bf(acc[mi][ni][r] + bv);
      } else {
        float* C = (float*)Cout;
#pragma unroll
        for (int r = 0; r < 4; r++)
          C[(size_t)(row + r) * 1024 + col] = acc[mi][ni][r] + bv;
      }
    }
  }
}

// =====================================================================
// KV GEMM 256x256 tile, 512 threads: C[16384][2048] = Kb @ [Wk^T;Wv^T]
// 8 waves of 128x64 (acc[8][4], 32 MFMA/iter/wave), BK=32, dbuf.
// Staging: 512 MB total (vs 768 at 256x128) -> staging-throughput win.
// cols <1024 -> kbp bf16 rowmajor (+bk); cols >=1024 -> vt[b][h][dh][nk] (+bv)
// =====================================================================
__global__ __launch_bounds__(512, 2) void gemm_kv(
    const unsigned short* __restrict__ A, const unsigned short* __restrict__ Bt,
    const float* __restrict__ biasK, const float* __restrict__ biasV,
    unsigned short* __restrict__ CK, unsigned short* __restrict__ CV) {
  __shared__ unsigned short As[2][4][256][8];  // 2 x 16 KB
  __shared__ unsigned short Bs[2][4][256][8];  // 2 x 16 KB

  const int tid = threadIdx.x;
  const int lane = tid & 63, w = tid >> 6;  // 8 waves
  const int wr = w & 1, wc = w >> 1;        // 2 row-groups x 4 col-groups
  const int qd = lane >> 4, l16 = lane & 15;
  const int m0 = blockIdx.y * 256, n0 = blockIdx.x * 256;

  floatx4 acc[8][4];
#pragma unroll
  for (int i = 0; i < 8; i++)
#pragma unroll
    for (int j = 0; j < 4; j++) { floatx4 z = {0.f, 0.f, 0.f, 0.f}; acc[i][j] = z; }

  // staging: 1024 16B-positions per tile; thread covers p=tid (chunk c0) and
  // p=tid+512 (chunk c0+2), row r0. chunk stride in LDS = 2048 shorts.
  const int r0 = tid & 255, c0 = tid >> 8;  // c0 in {0,1}
  const unsigned short* aptr = A + (size_t)(m0 + r0) * 1024 + c0 * 8;
  const unsigned short* bptr = Bt + (size_t)(n0 + r0) * 1024 + c0 * 8;
  unsigned short* dstA = &As[0][c0][r0][0];
  unsigned short* dstB = &Bs[0][c0][r0][0];

  lds_cp16(dstA, aptr);
  lds_cp16(dstA + 4096, aptr + 16);
  lds_cp16(dstB, bptr);
  lds_cp16(dstB + 4096, bptr + 16);

  for (int it = 0; it < 32; it++) {
    __syncthreads();
    if (it < 31) {
      const int nb = (it + 1) & 1, k0 = (it + 1) * 32;
      lds_cp16(dstA + nb * 8192, aptr + k0);
      lds_cp16(dstA + nb * 8192 + 4096, aptr + k0 + 16);
      lds_cp16(dstB + nb * 8192, bptr + k0);
      lds_cp16(dstB + nb * 8192 + 4096, bptr + k0 + 16);
    }
    const int cur = it & 1;
    short8 af[8], bf[4];
#pragma unroll
    for (int mi = 0; mi < 8; mi++)
      af[mi] = *(const short8*)&As[cur][qd][wr * 128 + mi * 16 + l16][0];
#pragma unroll
    for (int ni = 0; ni < 4; ni++)
      bf[ni] = *(const short8*)&Bs[cur][qd][wc * 64 + ni * 16 + l16][0];
#pragma unroll
    for (int mi = 0; mi < 8; mi++)
#pragma unroll
      for (int ni = 0; ni < 4; ni++)
        acc[mi][ni] =
            __builtin_amdgcn_mfma_f32_16x16x32_bf16(af[mi], bf[ni], acc[mi][ni], 0, 0, 0);
  }

#pragma unroll
  for (int mi = 0; mi < 8; mi++) {
#pragma unroll
    for (int ni = 0; ni < 4; ni++) {
      const int row = m0 + wr * 128 + mi * 16 + qd * 4;
      const int col = n0 + wc * 64 + ni * 16 + l16;
      if (col < 1024) {  // K half (wave-uniform: n0 multiple of 256)
        const float bv = biasK[col];
#pragma unroll
        for (int r = 0; r < 4; r++)
          CK[(size_t)(row + r) * 1024 + col] = f2bf(acc[mi][ni][r] + bv);
      } else {  // V half -> vt[b][h][dh][nk]
        const int vc = col - 1024;
        const float bv = biasV[vc];
        const int bb = row >> 11, nk = row & 2047;
        const int hh = vc >> 7, dh = vc & 127;
        ushortx4 pk;
        pk.x = f2bf(acc[mi][ni][0] + bv);
        pk.y = f2bf(acc[mi][ni][1] + bv);
        pk.z = f2bf(acc[mi][ni][2] + bv);
        pk.w = f2bf(acc[mi][ni][3] + bv);
        *(ushortx4*)&CV[(size_t)((bb * 8 + hh) * 128 + dh) * 2048 + nk] = pk;
      }
    }
  }
}

// =====================================================================
// Flash attention: 128 q-rows/block, BN=32 KV dbuf, single barrier/iter,
// Ps aliased over Qs, XCD-swizzled grid (bid%8 = b).
// =====================================================================
__global__ __launch_bounds__(256, 2) void attn(
    const unsigned short* __restrict__ qb, const unsigned short* __restrict__ kb,
    const unsigned short* __restrict__ vt, unsigned short* __restrict__ Ob) {
  __shared__ unsigned short smem[32768];

  const int tid = threadIdx.x;
  const int lane = tid & 63, w = tid >> 6;
  const int qd = lane >> 4, l16 = lane & 15;
  const int bid = blockIdx.x;
  const int qt = bid >> 6, bh = bid & 63;
  const int h = bh >> 3, b = bh & 7;
  const int m0 = qt * 128;

  const size_t qbase = ((size_t)(b * 1024 + m0)) * 1024 + h * 128;
  const size_t kbase = ((size_t)(b * 2048)) * 1024 + h * 128;
  const size_t vbase = ((size_t)((b * 8 + h) * 128)) * 2048;

#pragma unroll
  for (int i = 0; i < 8; i++) {
    const int p = i * 256 + tid;
    const int row = p & 127, c = p >> 7;
    lds_cp16(&smem[c * 1024 + row * 8], qb + qbase + (size_t)row * 1024 + c * 8);
  }
#pragma unroll
  for (int i = 0; i < 2; i++) {
    const int p = i * 256 + tid;
    const int kr = p & 31, kc = p >> 5;
    lds_cp16(&smem[16384 + kc * 256 + kr * 8], kb + kbase + (size_t)kr * 1024 + kc * 8);
    const int dh = p & 127, vc = p >> 7;
    lds_cp16(&smem[24576 + vc * 1024 + dh * 8], vt + vbase + (size_t)dh * 2048 + vc * 8);
  }
  __syncthreads();

  short8 qf[2][4];
#pragma unroll
  for (int mi = 0; mi < 2; mi++)
#pragma unroll
    for (int ks = 0; ks < 4; ks++)
      qf[mi][ks] =
          *(const short8*)&smem[(ks * 4 + qd) * 1024 + ((w * 2 + mi) * 16 + l16) * 8];
  __syncthreads();

  floatx4 oacc[2][8];
#pragma unroll
  for (int mi = 0; mi < 2; mi++)
#pragma unroll
    for (int ni = 0; ni < 8; ni++) { floatx4 z = {0.f, 0.f, 0.f, 0.f}; oacc[mi][ni] = z; }
  float lsum[2][4];
#pragma unroll
  for (int mi = 0; mi < 2; mi++)
#pragma unroll
    for (int r = 0; r < 4; r++) lsum[mi][r] = 0.f;

  for (int it = 0; it < 64; it++) {
    if (it) __syncthreads();
    if (it + 1 < 64) {
      const int nb = (it + 1) & 1, kv0 = (it + 1) * 32;
#pragma unroll
      for (int i = 0; i < 2; i++) {
        const int p = i * 256 + tid;
        const int kr = p & 31, kc = p >> 5;
        lds_cp16(&smem[16384 + nb * 4096 + kc * 256 + kr * 8],
                 kb + kbase + (size_t)(kv0 + kr) * 1024 + kc * 8);
        const int dh = p & 127, vc = p >> 7;
        lds_cp16(&smem[24576 + nb * 4096 + vc * 1024 + dh * 8],
                 vt + vbase + (size_t)dh * 2048 + kv0 + vc * 8);
      }
    }
    const int cur = it & 1;

    floatx4 sacc[2][2];
#pragma unroll
    for (int mi = 0; mi < 2; mi++)
#pragma unroll
      for (int ni = 0; ni < 2; ni++) { floatx4 z = {0.f, 0.f, 0.f, 0.f}; sacc[mi][ni] = z; }
#pragma unroll
    for (int ks = 0; ks < 4; ks++) {
      short8 b0 = *(const short8*)&smem[16384 + cur * 4096 + (ks * 4 + qd) * 256 + l16 * 8];
      short8 b1 =
          *(const short8*)&smem[16384 + cur * 4096 + (ks * 4 + qd) * 256 + (16 + l16) * 8];
#pragma unroll
      for (int mi = 0; mi < 2; mi++) {
        sacc[mi][0] = __builtin_amdgcn_mfma_f32_16x16x32_bf16(qf[mi][ks], b0, sacc[mi][0], 0, 0, 0);
        sacc[mi][1] = __builtin_amdgcn_mfma_f32_16x16x32_bf16(qf[mi][ks], b1, sacc[mi][1], 0, 0, 0);
      }
    }

#pragma unroll
    for (int mi = 0; mi < 2; mi++)
#pragma unroll
      for (int ni = 0; ni < 2; ni++) {
        const int kvl = ni * 16 + l16;
#pragma unroll
        for (int r = 0; r < 4; r++) {
          const float e = __expf(sacc[mi][ni][r] * 0.03125f);
          lsum[mi][r] += e;
          smem[(kvl >> 3) * 1024 + ((w * 2 + mi) * 16 + qd * 4 + r) * 8 + (kvl & 7)] = f2bf(e);
        }
      }

    short8 pf[2];
#pragma unroll
    for (int mi = 0; mi < 2; mi++)
      pf[mi] = *(const short8*)&smem[qd * 1024 + ((w * 2 + mi) * 16 + l16) * 8];
#pragma unroll
    for (int ni = 0; ni < 8; ni++) {
      const short8 vf = *(const short8*)&smem[24576 + cur * 4096 + qd * 1024 + (ni * 16 + l16) * 8];
#pragma unroll
      for (int mi = 0; mi < 2; mi++)
        oacc[mi][ni] = __builtin_amdgcn_mfma_f32_16x16x32_bf16(pf[mi], vf, oacc[mi][ni], 0, 0, 0);
    }
  }

  float inv[2][4];
#pragma unroll
  for (int mi = 0; mi < 2; mi++)
#pragma unroll
    for (int r = 0; r < 4; r++) {
      float s = lsum[mi][r];
      s += __shfl_xor(s, 1); s += __shfl_xor(s, 2);
      s += __shfl_xor(s, 4); s += __shfl_xor(s, 8);
      inv[mi][r] = 1.f / s;
    }

#pragma unroll
  for (int mi = 0; mi < 2; mi++)
#pragma unroll
    for (int ni = 0; ni < 8; ni++)
#pragma unroll
      for (int r = 0; r < 4; r++) {
        const int m = (w * 2 + mi) * 16 + qd * 4 + r;
        const int dh = ni * 16 + l16;
        const float qv = bf2f(qb[qbase + (size_t)m * 1024 + dh]);
        Ob[qbase + (size_t)m * 1024 + dh] = f2bf(qv + oacc[mi][ni][r] * inv[mi][r]);
      }
}

// =====================================================================
// Row LayerNorm over 1024 (bf16 -> bf16)
// =====================================================================
__global__ __launch_bounds__(256) void ln_rows(const unsigned short* __restrict__ X,
                                               const float* __restrict__ g,
                                               const float* __restrict__ bb,
                                               unsigned short* __restrict__ Y) {
  __shared__ float red[8];
  const int row = blockIdx.x, tid = threadIdx.x;
  const int w = tid >> 6, lane = tid & 63;
  const ushortx4 u = ((const ushortx4*)(X + (size_t)row * 1024))[tid];
  float x0 = bf2f(u.x), x1 = bf2f(u.y), x2 = bf2f(u.z), x3 = bf2f(u.w);
  float s = x0 + x1 + x2 + x3;
  float s2 = x0 * x0 + x1 * x1 + x2 * x2 + x3 * x3;
#pragma unroll
  for (int off = 1; off < 64; off <<= 1) { s += __shfl_xor(s, off); s2 += __shfl_xor(s2, off); }
  if (lane == 0) { red[w] = s; red[4 + w] = s2; }
  __syncthreads();
  s = red[0] + red[1] + red[2] + red[3];
  s2 = red[4] + red[5] + red[6] + red[7];
  const float mu = s * (1.f / 1024.f);
  const float rs = rsqrtf(s2 * (1.f / 1024.f) - mu * mu + 1e-5f);
  const floatx4 gv = ((const floatx4*)g)[tid];
  const floatx4 bv = ((const floatx4*)bb)[tid];
  ushortx4 o;
  o.x = f2bf((x0 - mu) * rs * gv.x + bv.x);
  o.y = f2bf((x1 - mu) * rs * gv.y + bv.y);
  o.z = f2bf((x2 - mu) * rs * gv.z + bv.z);
  o.w = f2bf((x3 - mu) * rs * gv.w + bv.w);
  ((ushortx4*)(Y + (size_t)row * 1024))[tid] = o;
}

// =====================================================================
// Final: out = LN(X1 + relu(Y), g1, b1)  (f32 out)
// =====================================================================
__global__ __launch_bounds__(256) void final_fuse(const unsigned short* __restrict__ X1,
                                                  const float* __restrict__ Yf,
                                                  const float* __restrict__ g,
                                                  const float* __restrict__ bb,
                                                  float* __restrict__ out) {
  __shared__ float red[8];
  const int row = blockIdx.x, tid = threadIdx.x;
  const int w = tid >> 6, lane = tid & 63;
  const ushortx4 u = ((const ushortx4*)(X1 + (size_t)row * 1024))[tid];
  const floatx4 yv = ((const floatx4*)(Yf + (size_t)row * 1024))[tid];
  float x0 = bf2f(u.x) + fmaxf(yv.x, 0.f);
  float x1 = bf2f(u.y) + fmaxf(yv.y, 0.f);
  float x2 = bf2f(u.z) + fmaxf(yv.z, 0.f);
  float x3 = bf2f(u.w) + fmaxf(yv.w, 0.f);
  float s = x0 + x1 + x2 + x3;
  float s2 = x0 * x0 + x1 * x1 + x2 * x2 + x3 * x3;
#pragma unroll
  for (int off = 1; off < 64; off <<= 1) { s += __shfl_xor(s, off); s2 += __shfl_xor(s2, off); }
  if (lane == 0) { red[w] = s; red[4 + w] = s2; }
  __syncthreads();
  s = red[0] + red[1] + red[2] + red[3];
  s2 = red[4] + red[5] + red[6] + red[7];
  const float mu = s * (1.f / 1024.f);
  const float rs = rsqrtf(s2 * (1.f / 1024.f) - mu * mu + 1e-5f);
  const floatx4 gv = ((const floatx4*)g)[tid];
  const floatx4 bv = ((const floatx4*)bb)[tid];
  floatx4 o;
  o.x = (x0 - mu) * rs * gv.x + bv.x;
  o.y = (x1 - mu) * rs * gv.y + bv.y;
  o.z = (x2 - mu) * rs * gv.z + bv.z;
  o.w = (x3 - mu) * rs * gv.w + bv.w;
  ((floatx4*)(out + (size_t)row * 1024))[tid] = o;
}

// =====================================================================
// Host launch
// =====================================================================
extern "C" void kernel_launch(void* const* d_in, const int* in_sizes, int n_in,
                              void* d_out, int out_size, void* d_ws, size_t ws_size,
                              hipStream_t stream) {
  (void)in_sizes; (void)n_in; (void)out_size; (void)ws_size;
  const float* Q  = (const float*)d_in[0];
  const float* K  = (const float*)d_in[1];
  const float* Wq = (const float*)d_in[2];
  const float* bq = (const float*)d_in[3];
  const float* Wk = (const float*)d_in[4];
  const float* bk = (const float*)d_in[5];
  const float* Wv = (const float*)d_in[6];
  const float* bv = (const float*)d_in[7];
  const float* Wo = (const float*)d_in[8];
  const float* bo = (const float*)d_in[9];
  const float* g0 = (const float*)d_in[10];
  const float* b0 = (const float*)d_in[11];
  const float* g1 = (const float*)d_in[12];
  const float* b1 = (const float*)d_in[13];
  float* out = (float*)d_out;

  char* ws = (char*)d_ws;
  const size_t MB = 1u << 20;
  unsigned short* Qb  = (unsigned short*)(ws + 0);         // 16 MB [later: O]
  unsigned short* Kb  = (unsigned short*)(ws + 16 * MB);   // 32 MB [later: X1]
  unsigned short* Wt  = (unsigned short*)(ws + 48 * MB);   // 8 MB stacked Wq|Wk|Wv|Wo (^T)
  unsigned short* qbp = (unsigned short*)(ws + 56 * MB);   // 16 MB
  unsigned short* kbp = (unsigned short*)(ws + 72 * MB);   // 32 MB [later: Yf f32]
  unsigned short* vtp = (unsigned short*)(ws + 104 * MB);  // 32 MB
  unsigned short* O   = Qb;
  unsigned short* X1  = Kb;
  float* Yf = (float*)(ws + 72 * MB);

  unsigned short* Wqt  = Wt;
  unsigned short* Wkvt = Wt + (size_t)1024 * 1024;  // [Wk^T ; Wv^T] = [2048][1024]
  unsigned short* Wot  = Wt + (size_t)3072 * 1024;

  cvt_bf16<<<8192, 256, 0, stream>>>(Q, Qb);
  cvt_bf16<<<16384, 256, 0, stream>>>(K, Kb);
  wtrans4<<<dim3(32, 32, 4), dim3(32, 8), 0, stream>>>(Wq, Wk, Wv, Wo, Wt);

  // Q projection -> qbp (bf16 rowmajor), 256x128 tiles
  gemm_bt<0><<<dim3(8, 32), 256, 0, stream>>>(Qb, Wqt, bq, qbp);
  // fused K+V projection, 256x256 tiles, 512 threads
  gemm_kv<<<dim3(8, 64), 512, 0, stream>>>(Kb, Wkvt, bk, bv, kbp, vtp);
  // attention (+ q residual) -> O bf16
  attn<<<512, 256, 0, stream>>>(qbp, kbp, vtp, O);
  // LN0
  ln_rows<<<8192, 256, 0, stream>>>(O, g0, b0, X1);
  // Y = X1 @ Wo + bo (f32), 256x128 tiles
  gemm_bt<1><<<dim3(8, 32), 256, 0, stream>>>(X1, Wot, bo, Yf);
  // out = LN(X1 + relu(Y))
  final_fuse<<<8192, 256, 0, stream>>>(X1, Yf, g1, b1, out);
}

// Round 5
// 478.677 us; speedup vs baseline: 1.0497x; 1.0497x over previous
//
#include <hip/hip_runtime.h>
#include <stdint.h>

#define DEVI static __device__ __forceinline__

typedef __attribute__((ext_vector_type(8))) short short8;
typedef __attribute__((ext_vector_type(4))) float floatx4;
typedef __attribute__((ext_vector_type(4))) unsigned short ushortx4;

// ---------- bf16 helpers ----------
DEVI unsigned short f2bf(float f) {
  union { float f; uint32_t u; } v; v.f = f;
  uint32_t r = v.u + 0x7FFFu + ((v.u >> 16) & 1u);
  return (unsigned short)(r >> 16);
}
DEVI float bf2f(unsigned short s) {
  union { uint32_t u; float f; } v; v.u = ((uint32_t)s) << 16;
  return v.f;
}

// ---------- async global->LDS 16B ----------
DEVI void lds_cp16(void* lds, const void* g) {
  __builtin_amdgcn_global_load_lds(
      (const __attribute__((address_space(1))) uint32_t*)g,
      reinterpret_cast<__attribute__((address_space(3))) uint32_t*>(
          (uint32_t)reinterpret_cast<uintptr_t>(lds)),
      16, 0, 0);
}

// =====================================================================
// f32 -> bf16 for Q (first 8192 blocks) and K (next 16384 blocks)
// =====================================================================
__global__ __launch_bounds__(256) void cvt_qk(const float* __restrict__ Q,
                                              const float* __restrict__ K,
                                              unsigned short* __restrict__ Qb,
                                              unsigned short* __restrict__ Kb) {
  const int bid = blockIdx.x;
  const float* src;
  unsigned short* dst;
  size_t i;
  if (bid < 8192) { src = Q; dst = Qb; i = (size_t)bid * 256 + threadIdx.x; }
  else            { src = K; dst = Kb; i = (size_t)(bid - 8192) * 256 + threadIdx.x; }
  const floatx4 v = ((const floatx4*)src)[i];
  ushortx4 o;
  o.x = f2bf(v.x); o.y = f2bf(v.y); o.z = f2bf(v.z); o.w = f2bf(v.w);
  ((ushortx4*)dst)[i] = o;
}

// =====================================================================
// All 4 weight transposes in one launch. z: 0=Wq,1=Wk,2=Wv,3=Wo.
// =====================================================================
__global__ __launch_bounds__(256) void wtrans4(const float* __restrict__ Wq,
                                               const float* __restrict__ Wk,
                                               const float* __restrict__ Wv,
                                               const float* __restrict__ Wo,
                                               unsigned short* __restrict__ Wt) {
  __shared__ float t[32][33];
  const int tx = threadIdx.x, ty = threadIdx.y;
  const int z = blockIdx.z;
  const float* W = (z == 0) ? Wq : (z == 1) ? Wk : (z == 2) ? Wv : Wo;
  unsigned short* D = Wt + (size_t)z * 1024 * 1024;
  const int c0 = blockIdx.x * 32, r0 = blockIdx.y * 32;
#pragma unroll
  for (int i = 0; i < 4; i++)
    t[ty + i * 8][tx] = W[(size_t)(r0 + ty + i * 8) * 1024 + c0 + tx];
  __syncthreads();
#pragma unroll
  for (int i = 0; i < 4; i++)
    D[(size_t)(c0 + ty + i * 8) * 1024 + r0 + tx] = f2bf(t[tx][ty + i * 8]);
}

// =====================================================================
// GEMM 128x128 tile (Q / Wo): C[8192][1024] = A @ Bt^T + bias
// 512 blocks 1D, XCD m-banded swizzle: xcd=bid&7 owns m-tiles [8*xcd,8*xcd+8)
// -> per-XCD working set A 2MB + B 2MB, lockstep k => L2 hits.
// EPI: 0 = bf16 rowmajor; 2 = O2 = X1 + relu(acc+bias), f32 rowmajor
// =====================================================================
template <int EPI>
__global__ __launch_bounds__(256, 3) void gemm_bt(
    const unsigned short* __restrict__ A, const unsigned short* __restrict__ Bt,
    const float* __restrict__ bias, const unsigned short* __restrict__ X1,
    void* __restrict__ Cout) {
  __shared__ unsigned short As[2][4][128][8];
  __shared__ unsigned short Bs[2][4][128][8];

  const int tid = threadIdx.x;
  const int lane = tid & 63, w = tid >> 6;
  const int wr = w >> 1, wc = w & 1;
  const int qd = lane >> 4, l16 = lane & 15;
  const int bid = blockIdx.x;
  const int xcd = bid & 7, loc = bid >> 3;
  const int m0 = (xcd * 8 + (loc & 7)) * 128;  // 64 m-tiles
  const int n0 = (loc >> 3) * 128;             // 8 n-tiles

  floatx4 acc[4][4];
#pragma unroll
  for (int i = 0; i < 4; i++)
#pragma unroll
    for (int j = 0; j < 4; j++) { floatx4 z = {0.f, 0.f, 0.f, 0.f}; acc[i][j] = z; }

  const int prow = tid & 127;
  const unsigned short* aptr = A + (size_t)(m0 + prow) * 1024 + ((tid >> 7) << 3);
  const unsigned short* bptr = Bt + (size_t)(n0 + prow) * 1024 + ((tid >> 7) << 3);
  const int dstoff = tid * 8;

  lds_cp16(&As[0][0][0][0] + dstoff, aptr);
  lds_cp16(&As[0][0][0][0] + dstoff + 2048, aptr + 16);
  lds_cp16(&Bs[0][0][0][0] + dstoff, bptr);
  lds_cp16(&Bs[0][0][0][0] + dstoff + 2048, bptr + 16);

  for (int it = 0; it < 32; it++) {
    __syncthreads();
    if (it < 31) {
      const int nb = (it + 1) & 1, k0 = (it + 1) * 32;
      lds_cp16(&As[nb][0][0][0] + dstoff, aptr + k0);
      lds_cp16(&As[nb][0][0][0] + dstoff + 2048, aptr + k0 + 16);
      lds_cp16(&Bs[nb][0][0][0] + dstoff, bptr + k0);
      lds_cp16(&Bs[nb][0][0][0] + dstoff + 2048, bptr + k0 + 16);
    }
    const int cur = it & 1;
    short8 af[4], bf[4];
#pragma unroll
    for (int mi = 0; mi < 4; mi++)
      af[mi] = *(const short8*)&As[cur][qd][wr * 64 + mi * 16 + l16][0];
#pragma unroll
    for (int ni = 0; ni < 4; ni++)
      bf[ni] = *(const short8*)&Bs[cur][qd][wc * 64 + ni * 16 + l16][0];
#pragma unroll
    for (int mi = 0; mi < 4; mi++)
#pragma unroll
      for (int ni = 0; ni < 4; ni++)
        acc[mi][ni] =
            __builtin_amdgcn_mfma_f32_16x16x32_bf16(af[mi], bf[ni], acc[mi][ni], 0, 0, 0);
  }

#pragma unroll
  for (int mi = 0; mi < 4; mi++) {
#pragma unroll
    for (int ni = 0; ni < 4; ni++) {
      const int row = m0 + wr * 64 + mi * 16 + qd * 4;
      const int col = n0 + wc * 64 + ni * 16 + l16;
      const float bv = bias[col];
      if constexpr (EPI == 0) {
        unsigned short* C = (unsigned short*)Cout;
#pragma unroll
        for (int r = 0; r < 4; r++)
          C[(size_t)(row + r) * 1024 + col] = f2bf(acc[mi][ni][r] + bv);
      } else {
        float* C = (float*)Cout;
#pragma unroll
        for (int r = 0; r < 4; r++) {
          const float x1 = bf2f(X1[(size_t)(row + r) * 1024 + col]);
          C[(size_t)(row + r) * 1024 + col] = x1 + fmaxf(acc[mi][ni][r] + bv, 0.f);
        }
      }
    }
  }
}

// =====================================================================
// KV GEMM 256x256 tile, 512 threads, XCD m-banded swizzle.
// 8 waves of 128x64 (acc[8][4]), BK=32, single-barrier dbuf.
// cols <1024 -> kbp bf16 rowmajor (+bk); cols >=1024 -> vt[b][h][dh][nk] (+bv)
// =====================================================================
__global__ __launch_bounds__(512, 2) void gemm_kv(
    const unsigned short* __restrict__ A, const unsigned short* __restrict__ Bt,
    const float* __restrict__ biasK, const float* __restrict__ biasV,
    unsigned short* __restrict__ CK, unsigned short* __restrict__ CV) {
  __shared__ unsigned short As[2][4][256][8];
  __shared__ unsigned short Bs[2][4][256][8];

  const int tid = threadIdx.x;
  const int lane = tid & 63, w = tid >> 6;
  const int wr = w & 1, wc = w >> 1;
  const int qd = lane >> 4, l16 = lane & 15;
  const int bid = blockIdx.x;
  const int xcd = bid & 7, loc = bid >> 3;
  const int m0 = (xcd * 8 + (loc & 7)) * 256;  // 64 m-tiles
  const int n0 = (loc >> 3) * 256;             // 8 n-tiles

  floatx4 acc[8][4];
#pragma unroll
  for (int i = 0; i < 8; i++)
#pragma unroll
    for (int j = 0; j < 4; j++) { floatx4 z = {0.f, 0.f, 0.f, 0.f}; acc[i][j] = z; }

  const int r0 = tid & 255, c0 = tid >> 8;
  const unsigned short* aptr = A + (size_t)(m0 + r0) * 1024 + c0 * 8;
  const unsigned short* bptr = Bt + (size_t)(n0 + r0) * 1024 + c0 * 8;
  unsigned short* dstA = &As[0][c0][r0][0];
  unsigned short* dstB = &Bs[0][c0][r0][0];

  lds_cp16(dstA, aptr);
  lds_cp16(dstA + 4096, aptr + 16);
  lds_cp16(dstB, bptr);
  lds_cp16(dstB + 4096, bptr + 16);

  for (int it = 0; it < 32; it++) {
    __syncthreads();
    if (it < 31) {
      const int nb = (it + 1) & 1, k0 = (it + 1) * 32;
      lds_cp16(dstA + nb * 8192, aptr + k0);
      lds_cp16(dstA + nb * 8192 + 4096, aptr + k0 + 16);
      lds_cp16(dstB + nb * 8192, bptr + k0);
      lds_cp16(dstB + nb * 8192 + 4096, bptr + k0 + 16);
    }
    const int cur = it & 1;
    short8 af[8], bf[4];
#pragma unroll
    for (int mi = 0; mi < 8; mi++)
      af[mi] = *(const short8*)&As[cur][qd][wr * 128 + mi * 16 + l16][0];
#pragma unroll
    for (int ni = 0; ni < 4; ni++)
      bf[ni] = *(const short8*)&Bs[cur][qd][wc * 64 + ni * 16 + l16][0];
#pragma unroll
    for (int mi = 0; mi < 8; mi++)
#pragma unroll
      for (int ni = 0; ni < 4; ni++)
        acc[mi][ni] =
            __builtin_amdgcn_mfma_f32_16x16x32_bf16(af[mi], bf[ni], acc[mi][ni], 0, 0, 0);
  }

#pragma unroll
  for (int mi = 0; mi < 8; mi++) {
#pragma unroll
    for (int ni = 0; ni < 4; ni++) {
      const int row = m0 + wr * 128 + mi * 16 + qd * 4;
      const int col = n0 + wc * 64 + ni * 16 + l16;
      if (col < 1024) {  // K half (wave-uniform: n0 multiple of 256)
        const float bv = biasK[col];
#pragma unroll
        for (int r = 0; r < 4; r++)
          CK[(size_t)(row + r) * 1024 + col] = f2bf(acc[mi][ni][r] + bv);
      } else {  // V half -> vt[b][h][dh][nk]
        const int vc = col - 1024;
        const float bv = biasV[vc];
        const int bb = row >> 11, nk = row & 2047;
        const int hh = vc >> 7, dh = vc & 127;
        ushortx4 pk;
        pk.x = f2bf(acc[mi][ni][0] + bv);
        pk.y = f2bf(acc[mi][ni][1] + bv);
        pk.z = f2bf(acc[mi][ni][2] + bv);
        pk.w = f2bf(acc[mi][ni][3] + bv);
        *(ushortx4*)&CV[(size_t)((bb * 8 + hh) * 128 + dh) * 2048 + nk] = pk;
      }
    }
  }
}

// =====================================================================
// Flash attention: 128 q-rows/block, BN=32 KV dbuf, single barrier/iter,
// Ps aliased over Qs, XCD-swizzled grid (bid%8 = b).
// =====================================================================
__global__ __launch_bounds__(256, 2) void attn(
    const unsigned short* __restrict__ qb, const unsigned short* __restrict__ kb,
    const unsigned short* __restrict__ vt, unsigned short* __restrict__ Ob) {
  __shared__ unsigned short smem[32768];

  const int tid = threadIdx.x;
  const int lane = tid & 63, w = tid >> 6;
  const int qd = lane >> 4, l16 = lane & 15;
  const int bid = blockIdx.x;
  const int qt = bid >> 6, bh = bid & 63;
  const int h = bh >> 3, b = bh & 7;
  const int m0 = qt * 128;

  const size_t qbase = ((size_t)(b * 1024 + m0)) * 1024 + h * 128;
  const size_t kbase = ((size_t)(b * 2048)) * 1024 + h * 128;
  const size_t vbase = ((size_t)((b * 8 + h) * 128)) * 2048;

#pragma unroll
  for (int i = 0; i < 8; i++) {
    const int p = i * 256 + tid;
    const int row = p & 127, c = p >> 7;
    lds_cp16(&smem[c * 1024 + row * 8], qb + qbase + (size_t)row * 1024 + c * 8);
  }
#pragma unroll
  for (int i = 0; i < 2; i++) {
    const int p = i * 256 + tid;
    const int kr = p & 31, kc = p >> 5;
    lds_cp16(&smem[16384 + kc * 256 + kr * 8], kb + kbase + (size_t)kr * 1024 + kc * 8);
    const int dh = p & 127, vc = p >> 7;
    lds_cp16(&smem[24576 + vc * 1024 + dh * 8], vt + vbase + (size_t)dh * 2048 + vc * 8);
  }
  __syncthreads();

  short8 qf[2][4];
#pragma unroll
  for (int mi = 0; mi < 2; mi++)
#pragma unroll
    for (int ks = 0; ks < 4; ks++)
      qf[mi][ks] =
          *(const short8*)&smem[(ks * 4 + qd) * 1024 + ((w * 2 + mi) * 16 + l16) * 8];
  __syncthreads();

  floatx4 oacc[2][8];
#pragma unroll
  for (int mi = 0; mi < 2; mi++)
#pragma unroll
    for (int ni = 0; ni < 8; ni++) { floatx4 z = {0.f, 0.f, 0.f, 0.f}; oacc[mi][ni] = z; }
  float lsum[2][4];
#pragma unroll
  for (int mi = 0; mi < 2; mi++)
#pragma unroll
    for (int r = 0; r < 4; r++) lsum[mi][r] = 0.f;

  for (int it = 0; it < 64; it++) {
    if (it) __syncthreads();
    if (it + 1 < 64) {
      const int nb = (it + 1) & 1, kv0 = (it + 1) * 32;
#pragma unroll
      for (int i = 0; i < 2; i++) {
        const int p = i * 256 + tid;
        const int kr = p & 31, kc = p >> 5;
        lds_cp16(&smem[16384 + nb * 4096 + kc * 256 + kr * 8],
                 kb + kbase + (size_t)(kv0 + kr) * 1024 + kc * 8);
        const int dh = p & 127, vc = p >> 7;
        lds_cp16(&smem[24576 + nb * 4096 + vc * 1024 + dh * 8],
                 vt + vbase + (size_t)dh * 2048 + kv0 + vc * 8);
      }
    }
    const int cur = it & 1;

    floatx4 sacc[2][2];
#pragma unroll
    for (int mi = 0; mi < 2; mi++)
#pragma unroll
      for (int ni = 0; ni < 2; ni++) { floatx4 z = {0.f, 0.f, 0.f, 0.f}; sacc[mi][ni] = z; }
#pragma unroll
    for (int ks = 0; ks < 4; ks++) {
      short8 b0 = *(const short8*)&smem[16384 + cur * 4096 + (ks * 4 + qd) * 256 + l16 * 8];
      short8 b1 =
          *(const short8*)&smem[16384 + cur * 4096 + (ks * 4 + qd) * 256 + (16 + l16) * 8];
#pragma unroll
      for (int mi = 0; mi < 2; mi++) {
        sacc[mi][0] = __builtin_amdgcn_mfma_f32_16x16x32_bf16(qf[mi][ks], b0, sacc[mi][0], 0, 0, 0);
        sacc[mi][1] = __builtin_amdgcn_mfma_f32_16x16x32_bf16(qf[mi][ks], b1, sacc[mi][1], 0, 0, 0);
      }
    }

#pragma unroll
    for (int mi = 0; mi < 2; mi++)
#pragma unroll
      for (int ni = 0; ni < 2; ni++) {
        const int kvl = ni * 16 + l16;
#pragma unroll
        for (int r = 0; r < 4; r++) {
          const float e = __expf(sacc[mi][ni][r] * 0.03125f);
          lsum[mi][r] += e;
          smem[(kvl >> 3) * 1024 + ((w * 2 + mi) * 16 + qd * 4 + r) * 8 + (kvl & 7)] = f2bf(e);
        }
      }

    short8 pf[2];
#pragma unroll
    for (int mi = 0; mi < 2; mi++)
      pf[mi] = *(const short8*)&smem[qd * 1024 + ((w * 2 + mi) * 16 + l16) * 8];
#pragma unroll
    for (int ni = 0; ni < 8; ni++) {
      const short8 vf = *(const short8*)&smem[24576 + cur * 4096 + qd * 1024 + (ni * 16 + l16) * 8];
#pragma unroll
      for (int mi = 0; mi < 2; mi++)
        oacc[mi][ni] = __builtin_amdgcn_mfma_f32_16x16x32_bf16(pf[mi], vf, oacc[mi][ni], 0, 0, 0);
    }
  }

  float inv[2][4];
#pragma unroll
  for (int mi = 0; mi < 2; mi++)
#pragma unroll
    for (int r = 0; r < 4; r++) {
      float s = lsum[mi][r];
      s += __shfl_xor(s, 1); s += __shfl_xor(s, 2);
      s += __shfl_xor(s, 4); s += __shfl_xor(s, 8);
      inv[mi][r] = 1.f / s;
    }

#pragma unroll
  for (int mi = 0; mi < 2; mi++)
#pragma unroll
    for (int ni = 0; ni < 8; ni++)
#pragma unroll
      for (int r = 0; r < 4; r++) {
        const int m = (w * 2 + mi) * 16 + qd * 4 + r;
        const int dh = ni * 16 + l16;
        const float qv = bf2f(qb[qbase + (size_t)m * 1024 + dh]);
        Ob[qbase + (size_t)m * 1024 + dh] = f2bf(qv + oacc[mi][ni][r] * inv[mi][r]);
      }
}

// =====================================================================
// Row LayerNorm over 1024 (bf16 -> bf16)
// =====================================================================
__global__ __launch_bounds__(256) void ln_rows(const unsigned short* __restrict__ X,
                                               const float* __restrict__ g,
                                               const float* __restrict__ bb,
                                               unsigned short* __restrict__ Y) {
  __shared__ float red[8];
  const int row = blockIdx.x, tid = threadIdx.x;
  const int w = tid >> 6, lane = tid & 63;
  const ushortx4 u = ((const ushortx4*)(X + (size_t)row * 1024))[tid];
  float x0 = bf2f(u.x), x1 = bf2f(u.y), x2 = bf2f(u.z), x3 = bf2f(u.w);
  float s = x0 + x1 + x2 + x3;
  float s2 = x0 * x0 + x1 * x1 + x2 * x2 + x3 * x3;
#pragma unroll
  for (int off = 1; off < 64; off <<= 1) { s += __shfl_xor(s, off); s2 += __shfl_xor(s2, off); }
  if (lane == 0) { red[w] = s; red[4 + w] = s2; }
  __syncthreads();
  s = red[0] + red[1] + red[2] + red[3];
  s2 = red[4] + red[5] + red[6] + red[7];
  const float mu = s * (1.f / 1024.f);
  const float rs = rsqrtf(s2 * (1.f / 1024.f) - mu * mu + 1e-5f);
  const floatx4 gv = ((const floatx4*)g)[tid];
  const floatx4 bv = ((const floatx4*)bb)[tid];
  ushortx4 o;
  o.x = f2bf((x0 - mu) * rs * gv.x + bv.x);
  o.y = f2bf((x1 - mu) * rs * gv.y + bv.y);
  o.z = f2bf((x2 - mu) * rs * gv.z + bv.z);
  o.w = f2bf((x3 - mu) * rs * gv.w + bv.w);
  ((ushortx4*)(Y + (size_t)row * 1024))[tid] = o;
}

// =====================================================================
// Row LayerNorm over 1024 (f32 -> f32) for the final output
// =====================================================================
__global__ __launch_bounds__(256) void ln_f32(const float* __restrict__ X,
                                              const float* __restrict__ g,
                                              const float* __restrict__ bb,
                                              float* __restrict__ out) {
  __shared__ float red[8];
  const int row = blockIdx.x, tid = threadIdx.x;
  const int w = tid >> 6, lane = tid & 63;
  const floatx4 xv = ((const floatx4*)(X + (size_t)row * 1024))[tid];
  float x0 = xv.x, x1 = xv.y, x2 = xv.z, x3 = xv.w;
  float s = x0 + x1 + x2 + x3;
  float s2 = x0 * x0 + x1 * x1 + x2 * x2 + x3 * x3;
#pragma unroll
  for (int off = 1; off < 64; off <<= 1) { s += __shfl_xor(s, off); s2 += __shfl_xor(s2, off); }
  if (lane == 0) { red[w] = s; red[4 + w] = s2; }
  __syncthreads();
  s = red[0] + red[1] + red[2] + red[3];
  s2 = red[4] + red[5] + red[6] + red[7];
  const float mu = s * (1.f / 1024.f);
  const float rs = rsqrtf(s2 * (1.f / 1024.f) - mu * mu + 1e-5f);
  const floatx4 gv = ((const floatx4*)g)[tid];
  const floatx4 bv = ((const floatx4*)bb)[tid];
  floatx4 o;
  o.x = (x0 - mu) * rs * gv.x + bv.x;
  o.y = (x1 - mu) * rs * gv.y + bv.y;
  o.z = (x2 - mu) * rs * gv.z + bv.z;
  o.w = (x3 - mu) * rs * gv.w + bv.w;
  ((floatx4*)(out + (size_t)row * 1024))[tid] = o;
}

// =====================================================================
// Host launch
// =====================================================================
extern "C" void kernel_launch(void* const* d_in, const int* in_sizes, int n_in,
                              void* d_out, int out_size, void* d_ws, size_t ws_size,
                              hipStream_t stream) {
  (void)in_sizes; (void)n_in; (void)out_size; (void)ws_size;
  const float* Q  = (const float*)d_in[0];
  const float* K  = (const float*)d_in[1];
  const float* Wq = (const float*)d_in[2];
  const float* bq = (const float*)d_in[3];
  const float* Wk = (const float*)d_in[4];
  const float* bk = (const float*)d_in[5];
  const float* Wv = (const float*)d_in[6];
  const float* bv = (const float*)d_in[7];
  const float* Wo = (const float*)d_in[8];
  const float* bo = (const float*)d_in[9];
  const float* g0 = (const float*)d_in[10];
  const float* b0 = (const float*)d_in[11];
  const float* g1 = (const float*)d_in[12];
  const float* b1 = (const float*)d_in[13];
  float* out = (float*)d_out;

  char* ws = (char*)d_ws;
  const size_t MB = 1u << 20;
  unsigned short* Qb  = (unsigned short*)(ws + 0);         // 16 MB [later: O]
  unsigned short* Kb  = (unsigned short*)(ws + 16 * MB);   // 32 MB [later: X1]
  unsigned short* Wt  = (unsigned short*)(ws + 48 * MB);   // 8 MB stacked Wq|Wk|Wv|Wo (^T)
  unsigned short* qbp = (unsigned short*)(ws + 56 * MB);   // 16 MB
  unsigned short* kbp = (unsigned short*)(ws + 72 * MB);   // 32 MB [later: O2 f32]
  unsigned short* vtp = (unsigned short*)(ws + 104 * MB);  // 32 MB
  unsigned short* O   = Qb;
  unsigned short* X1  = Kb;
  float* O2 = (float*)(ws + 72 * MB);

  unsigned short* Wqt  = Wt;
  unsigned short* Wkvt = Wt + (size_t)1024 * 1024;  // [Wk^T ; Wv^T] = [2048][1024]
  unsigned short* Wot  = Wt + (size_t)3072 * 1024;

  cvt_qk<<<24576, 256, 0, stream>>>(Q, K, Qb, Kb);
  wtrans4<<<dim3(32, 32, 4), dim3(32, 8), 0, stream>>>(Wq, Wk, Wv, Wo, Wt);

  // Q projection -> qbp (bf16 rowmajor), 128x128 tiles, XCD m-banded
  gemm_bt<0><<<512, 256, 0, stream>>>(Qb, Wqt, bq, nullptr, qbp);
  // fused K+V projection, 256x256 tiles, XCD m-banded
  gemm_kv<<<512, 512, 0, stream>>>(Kb, Wkvt, bk, bv, kbp, vtp);
  // attention (+ q residual) -> O bf16
  attn<<<512, 256, 0, stream>>>(qbp, kbp, vtp, O);
  // LN0
  ln_rows<<<8192, 256, 0, stream>>>(O, g0, b0, X1);
  // O2 = X1 + relu(X1 @ Wo + bo)  (f32), XCD m-banded
  gemm_bt<2><<<512, 256, 0, stream>>>(X1, Wot, bo, X1, O2);
  // out = LN(O2)
  ln_f32<<<8192, 256, 0, stream>>>(O2, g1, b1, out);
}